// Round 11
// baseline (425.235 us; speedup 1.0000x reference)
//
#include <hip/hip_runtime.h>
#include <stdint.h>

#define NN 50000
#define NE 800000
#define NB 196      // ceil(NN/256)
#define NCH 128     // edge chunks
#define CHSZ 6250   // NE / NCH (exact)
#define NR 4        // dst ranges
#define RSZ 16384   // dst per range (4*16384 >= NN); 64KB LDS uint hist

typedef short short8 __attribute__((ext_vector_type(8)));
typedef float f32x4 __attribute__((ext_vector_type(4)));
typedef unsigned int uint;
typedef unsigned short ushort;

__device__ __forceinline__ uint rne_bf16(float f) {
    uint x = __float_as_uint(f);
    return (x + 0x7FFFu + ((x >> 16) & 1u)) >> 16;  // round-to-nearest-even
}
__device__ __forceinline__ float bf_lo(uint d) { return __uint_as_float(d << 16); }
__device__ __forceinline__ float bf_hi(uint d) { return __uint_as_float(d & 0xFFFF0000u); }

// ---------------- int64-vs-int32 edge_index autodetect ----------------
__global__ void k_detect(const int* __restrict__ ei, int* __restrict__ flag) {
    int l = threadIdx.x;
    int v = (l < 16) ? ei[2 * l + 1] : 0;
    unsigned long long nz = __ballot(v != 0);
    if (l == 0 && blockIdx.x == 0) *flag = (nz == 0ULL) ? 1 : 0;
}

// ---------------- CSR build, zero global atomics --------------------------
// Pass A: per (chunk, dst-range) LDS histogram of dst.
__global__ __launch_bounds__(256) void k_hist(const int* __restrict__ ei,
                                              const int* __restrict__ flag,
                                              ushort* __restrict__ hist) {
    __shared__ uint lh[RSZ];  // 64KB
    int c = blockIdx.x >> 2;
    int d0 = (blockIdx.x & 3) * RSZ;
    for (int i = threadIdx.x; i < RSZ; i += 256) lh[i] = 0;
    __syncthreads();
    int is64 = *flag;
    int base = c * CHSZ;
    for (int i = threadIdx.x; i < CHSZ; i += 256) {
        int e = base + i;
        int dv = is64 ? ei[2 * NE + 2 * e] : ei[NE + e];
        int rel = dv - d0;
        if ((unsigned)rel < RSZ) atomicAdd(&lh[rel], 1u);
    }
    __syncthreads();
    int lim = min(RSZ, NN - d0);
    for (int i = threadIdx.x; i < lim; i += 256)
        hist[(size_t)c * NN + d0 + i] = (ushort)lh[i];
}

// Per-dst prefix over chunks: coff[c][d] = #edges with dst d in chunks < c.
__global__ __launch_bounds__(256) void k_colscan(const ushort* __restrict__ hist,
                                                 ushort* __restrict__ coff,
                                                 int* __restrict__ deg) {
    int d = blockIdx.x * 256 + threadIdx.x;
    if (d >= NN) return;
    int run = 0;
    for (int c = 0; c < NCH; c++) {
        coff[(size_t)c * NN + d] = (ushort)run;
        run += hist[(size_t)c * NN + d];
    }
    deg[d] = run;
}

// ---------------- multi-block scan over deg -> row_ptr ----------------
__global__ __launch_bounds__(256) void k_blocksum(const int* __restrict__ deg,
                                                  int* __restrict__ bsum) {
    __shared__ int s[256];
    int i = blockIdx.x * 256 + threadIdx.x;
    s[threadIdx.x] = (i < NN) ? deg[i] : 0;
    __syncthreads();
    for (int off = 128; off > 0; off >>= 1) {
        if (threadIdx.x < off) s[threadIdx.x] += s[threadIdx.x + off];
        __syncthreads();
    }
    if (threadIdx.x == 0) bsum[blockIdx.x] = s[0];
}

__global__ __launch_bounds__(256) void k_scanb(const int* __restrict__ bsum,
                                               int* __restrict__ boff) {
    __shared__ int s[256];
    int t = threadIdx.x;
    s[t] = (t < NB) ? bsum[t] : 0;
    __syncthreads();
    for (int off = 1; off < 256; off <<= 1) {
        int v = s[t];
        int a = (t >= off) ? s[t - off] : 0;
        __syncthreads();
        s[t] = v + a;
        __syncthreads();
    }
    if (t < NB) boff[t] = (t == 0) ? 0 : s[t - 1];
}

__global__ __launch_bounds__(256) void k_writeptr(const int* __restrict__ deg,
                                                  const int* __restrict__ boff,
                                                  int* __restrict__ row_ptr,
                                                  float* __restrict__ rinv) {
    __shared__ int s[256];
    int b = blockIdx.x, t = threadIdx.x;
    int i = b * 256 + t;
    int d = (i < NN) ? deg[i] : 0;
    s[t] = d;
    __syncthreads();
    for (int off = 1; off < 256; off <<= 1) {
        int v = s[t];
        int a = (t >= off) ? s[t - off] : 0;
        __syncthreads();
        s[t] = v + a;
        __syncthreads();
    }
    if (i < NN) {
        int pos = boff[b] + s[t] - d;
        row_ptr[i] = pos;
        rinv[i] = 1.0f / (float)max(d, 1);
    }
    if (b == 0 && t == 0) row_ptr[NN] = NE;
}

// Pass B: deterministic fill via LDS local-rank + coff, no global atomics.
__global__ __launch_bounds__(256) void k_fill2(const int* __restrict__ ei,
                                               const int* __restrict__ flag,
                                               const int* __restrict__ row_ptr,
                                               const ushort* __restrict__ coff,
                                               ushort* __restrict__ col) {
    __shared__ uint lh[RSZ];
    int c = blockIdx.x >> 2;
    int d0 = (blockIdx.x & 3) * RSZ;
    for (int i = threadIdx.x; i < RSZ; i += 256) lh[i] = 0;
    __syncthreads();
    int is64 = *flag;
    int base = c * CHSZ;
    for (int i = threadIdx.x; i < CHSZ; i += 256) {
        int e = base + i;
        int dv = is64 ? ei[2 * NE + 2 * e] : ei[NE + e];
        int rel = dv - d0;
        if ((unsigned)rel < RSZ) {
            int sv = is64 ? ei[2 * e] : ei[e];
            uint lrk = atomicAdd(&lh[rel], 1u);
            int p = row_ptr[dv] + (int)coff[(size_t)c * NN + dv] + (int)lrk;
            col[p] = (ushort)sv;
        }
    }
}

// ---------------- one-time casts to bf16 ----------------
__global__ __launch_bounds__(256) void k_cast_x(const float* __restrict__ x,
                                                ushort* __restrict__ xbf) {
    int i = blockIdx.x * 256 + threadIdx.x;  // 1.6M threads, 4 floats each
    float4 v = ((const float4*)x)[i];
    uint2 o;
    o.x = rne_bf16(v.x) | (rne_bf16(v.y) << 16);
    o.y = rne_bf16(v.z) | (rne_bf16(v.w) << 16);
    ((uint2*)xbf)[i] = o;
}

struct Ptrs8 { const float* p[8]; };
__global__ __launch_bounds__(256) void k_cvtW(Ptrs8 ps, ushort* __restrict__ wbf) {
    int idx = blockIdx.x * 256 + threadIdx.x;  // 0..131071
    int m = idx >> 14;
    int off = idx & 16383;
    wbf[idx] = (ushort)rne_bf16(ps.p[m][off]);
}

// ---------------- mean aggregation (measured-best structure) ------------------
// One wave per node; lane = bf16 pair. One col load covers 64 edges; row
// gathers are independent 256B coalesced wave loads (masked ragged tail).
// ~50us/layer floor: chip-level random-64B-line service bound (sc0, occupancy,
// MLP variants all within ~10%).
__global__ __launch_bounds__(256) void k_agg3(const ushort* __restrict__ h,
                                              const int* __restrict__ row_ptr,
                                              const ushort* __restrict__ col,
                                              const float* __restrict__ rinv,
                                              ushort* __restrict__ mean) {
    int node = blockIdx.x * 4 + (threadIdx.x >> 6);
    if (node >= NN) return;
    int lane = threadIdx.x & 63;
    int beg = row_ptr[node], end = row_ptr[node + 1];
    const uint* hp = (const uint*)h;  // row = 64 uints (128 bf16)
    float a0 = 0.f, a1 = 0.f;
    for (int b = beg; b < end; b += 64) {   // one iteration for deg <= 64
        int n = min(64, end - b);
        int c = (int)col[b + min(lane, n - 1)];
        for (int j0 = 0; j0 < n; j0 += 8) {
#pragma unroll
            for (int j = 0; j < 8; j++) {
                int jj = j0 + j;                     // wave-uniform
                int s = __shfl(c, min(jj, n - 1));   // uniform broadcast
                uint v = hp[s * 64 + lane];          // coalesced 256B row
                float m = (jj < n) ? 1.f : 0.f;
                a0 = fmaf(m, bf_lo(v), a0);
                a1 = fmaf(m, bf_hi(v), a1);
            }
        }
    }
    float r = rinv[node];
    ((uint*)mean)[node * 64 + lane] = rne_bf16(a0 * r) | (rne_bf16(a1 * r) << 16);
}

// ---------------- MFMA GEMM: out = mean@Wl^T + h@Wr^T + b (+ReLU) -------------
__global__ __launch_bounds__(256) void k_gemm_mfma(
    const ushort* __restrict__ Am, const ushort* __restrict__ Ah,
    const ushort* __restrict__ Wlb, const ushort* __restrict__ Wrb,
    const float* __restrict__ bias, float* __restrict__ outf,
    ushort* __restrict__ outb, int relu) {
    const int lane = threadIdx.x & 63;
    const int wave = threadIdx.x >> 6;
    const int l15 = lane & 15;
    const int quad = lane >> 4;
    const int m0 = blockIdx.x * 64 + wave * 16;

    f32x4 acc[8];
#pragma unroll
    for (int t = 0; t < 8; t++) acc[t] = (f32x4){0.f, 0.f, 0.f, 0.f};

    int arow = min(m0 + l15, NN - 1);  // clamp loads; stores guarded below
    const ushort* Arm = Am + (size_t)arow * 128 + quad * 8;
    const ushort* Arh = Ah + (size_t)arow * 128 + quad * 8;
    const int wro = quad * 8;

#pragma unroll
    for (int half = 0; half < 2; half++) {
        const ushort* Ar = half ? Arh : Arm;
        const ushort* W = half ? Wrb : Wlb;
#pragma unroll
        for (int k0 = 0; k0 < 128; k0 += 32) {
            short8 a = *(const short8*)(Ar + k0);
#pragma unroll
            for (int t = 0; t < 8; t++) {
                short8 b = *(const short8*)(W + (size_t)(t * 16 + l15) * 128 + k0 + wro);
                acc[t] = __builtin_amdgcn_mfma_f32_16x16x32_bf16(a, b, acc[t], 0, 0, 0);
            }
        }
    }

    float bb[8];
#pragma unroll
    for (int t = 0; t < 8; t++) bb[t] = bias[t * 16 + l15];

#pragma unroll
    for (int r = 0; r < 4; r++) {
        int row = m0 + quad * 4 + r;  // C/D: row = quad*4 + reg
        if (row < NN) {
#pragma unroll
            for (int t = 0; t < 8; t++) {
                float v = acc[t][r] + bb[t];
                if (relu) v = fmaxf(v, 0.f);
                if (outb) outb[(size_t)row * 128 + t * 16 + l15] = (ushort)rne_bf16(v);
                else outf[(size_t)row * 128 + t * 16 + l15] = v;
            }
        }
    }
}

extern "C" void kernel_launch(void* const* d_in, const int* in_sizes, int n_in,
                              void* d_out, int out_size, void* d_ws, size_t ws_size,
                              hipStream_t stream) {
    const float* x = (const float*)d_in[0];
    const int* ei = (const int*)d_in[1];
    const float* Wl[4] = {(const float*)d_in[2], (const float*)d_in[5],
                          (const float*)d_in[8], (const float*)d_in[11]};
    const float* bl[4] = {(const float*)d_in[3], (const float*)d_in[6],
                          (const float*)d_in[9], (const float*)d_in[12]};
    const float* Wr[4] = {(const float*)d_in[4], (const float*)d_in[7],
                          (const float*)d_in[10], (const float*)d_in[13]};
    float* out = (float*)d_out;

    char* p = (char*)d_ws;
    auto take = [&](size_t bytes) -> char* {
        char* r = p;
        p += (bytes + 255) & ~(size_t)255;
        return r;
    };
    int* flag = (int*)take(4);
    int* deg = (int*)take(NN * 4);
    int* row_ptr = (int*)take((NN + 1) * 4);
    float* rinv = (float*)take(NN * 4);
    int* bsum = (int*)take(NB * 4);
    int* boff = (int*)take(NB * 4);
    ushort* hist = (ushort*)take((size_t)NCH * NN * 2);   // 12.8MB
    ushort* coff = (ushort*)take((size_t)NCH * NN * 2);   // 12.8MB
    ushort* col = (ushort*)take((size_t)NE * 2 + 256);    // +pad
    ushort* xbf = (ushort*)take((size_t)NN * 128 * 2);
    ushort* h1 = (ushort*)take((size_t)NN * 128 * 2);
    ushort* h2 = (ushort*)take((size_t)NN * 128 * 2);
    ushort* meanbf = (ushort*)take((size_t)NN * 128 * 2);
    ushort* wbf = (ushort*)take(8 * 16384 * 2);

    // CSR build (zero global atomics; reused by all 4 layers)
    k_detect<<<1, 64, 0, stream>>>(ei, flag);
    k_hist<<<NCH * NR, 256, 0, stream>>>(ei, flag, hist);
    k_colscan<<<NB, 256, 0, stream>>>(hist, coff, deg);
    k_blocksum<<<NB, 256, 0, stream>>>(deg, bsum);
    k_scanb<<<1, 256, 0, stream>>>(bsum, boff);
    k_writeptr<<<NB, 256, 0, stream>>>(deg, boff, row_ptr, rinv);
    k_fill2<<<NCH * NR, 256, 0, stream>>>(ei, flag, row_ptr, coff, col);

    // one-time bf16 casts
    k_cast_x<<<(NN * 128 / 4) / 256, 256, 0, stream>>>(x, xbf);
    Ptrs8 ps;
    ps.p[0] = Wl[0]; ps.p[1] = Wr[0]; ps.p[2] = Wl[1]; ps.p[3] = Wr[1];
    ps.p[4] = Wl[2]; ps.p[5] = Wr[2]; ps.p[6] = Wl[3]; ps.p[7] = Wr[3];
    k_cvtW<<<512, 256, 0, stream>>>(ps, wbf);

    const ushort* h = xbf;
    ushort* houts[4] = {h1, h2, h1, nullptr};  // final layer -> fp32 d_out
    for (int l = 0; l < 4; l++) {
        k_agg3<<<(NN + 3) / 4, 256, 0, stream>>>(h, row_ptr, col, rinv, meanbf);
        k_gemm_mfma<<<(NN + 63) / 64, 256, 0, stream>>>(
            meanbf, h, wbf + (size_t)(2 * l) * 16384,
            wbf + (size_t)(2 * l + 1) * 16384, bl[l], out, houts[l],
            l == 0 ? 1 : 0);
        h = houts[l];
    }
}

// Round 12
// 418.916 us; speedup vs baseline: 1.0151x; 1.0151x over previous
//
#include <hip/hip_runtime.h>
#include <stdint.h>

#define NN 50000
#define NE 800000
#define NB 196        // ceil(NN/256)
#define CAST_B 6250   // NN*128/4/256 exactly
#define CVTW_B 512    // 8*16384/256
#define CNT_B 3125    // NE/256 exactly

typedef short short8 __attribute__((ext_vector_type(8)));
typedef float f32x4 __attribute__((ext_vector_type(4)));
typedef unsigned int uint;
typedef unsigned short ushort;

__device__ __forceinline__ uint rne_bf16(float f) {
    uint x = __float_as_uint(f);
    return (x + 0x7FFFu + ((x >> 16) & 1u)) >> 16;  // round-to-nearest-even
}
__device__ __forceinline__ float bf_lo(uint d) { return __uint_as_float(d << 16); }
__device__ __forceinline__ float bf_hi(uint d) { return __uint_as_float(d & 0xFFFF0000u); }

// int64 edge_index => int32 view is [lo,hi,lo,hi,...] with hi==0 (vals<50000).
// For int32 data these words are random node ids; P(all 4 zero) ~ 2e-19.
__device__ __forceinline__ int ei_is64(const int* __restrict__ ei) {
    return (ei[1] | ei[3] | ei[5] | ei[7]) == 0;
}

struct Ptrs8 { const float* p[8]; };

// ---------------- packed prep: x-cast | W-cast | degree count -----------------
// Independent jobs in one dispatch: streaming casts co-reside with the
// atomic-latency-bound count (different pipes), and 3 launches become 1.
__global__ __launch_bounds__(256) void k_prep(
    const float* __restrict__ x, ushort* __restrict__ xbf, Ptrs8 ps,
    ushort* __restrict__ wbf, const int* __restrict__ ei,
    int* __restrict__ deg, ushort* __restrict__ rank) {
    int b = blockIdx.x;
    if (b < CAST_B) {                       // cast x -> bf16 (4 floats/thread)
        int i = b * 256 + threadIdx.x;
        float4 v = ((const float4*)x)[i];
        uint2 o;
        o.x = rne_bf16(v.x) | (rne_bf16(v.y) << 16);
        o.y = rne_bf16(v.z) | (rne_bf16(v.w) << 16);
        ((uint2*)xbf)[i] = o;
    } else if (b < CAST_B + CVTW_B) {       // cast 8 weight matrices -> bf16
        int idx = (b - CAST_B) * 256 + threadIdx.x;
        int m = idx >> 14;
        int off = idx & 16383;
        wbf[idx] = (ushort)rne_bf16(ps.p[m][off]);
    } else {                                // degree count + arrival rank
        int e = (b - CAST_B - CVTW_B) * 256 + threadIdx.x;
        int is64 = ei_is64(ei);
        int d = is64 ? ei[2 * NE + 2 * e] : ei[NE + e];
        int rk = atomicAdd(&deg[d], 1);
        rank[e] = (ushort)rk;
    }
}

// ---------------- multi-block scan over deg -> row_ptr ----------------
__global__ __launch_bounds__(256) void k_blocksum(const int* __restrict__ deg,
                                                  int* __restrict__ bsum) {
    __shared__ int s[256];
    int i = blockIdx.x * 256 + threadIdx.x;
    s[threadIdx.x] = (i < NN) ? deg[i] : 0;
    __syncthreads();
    for (int off = 128; off > 0; off >>= 1) {
        if (threadIdx.x < off) s[threadIdx.x] += s[threadIdx.x + off];
        __syncthreads();
    }
    if (threadIdx.x == 0) bsum[blockIdx.x] = s[0];
}

__global__ __launch_bounds__(256) void k_scanb(const int* __restrict__ bsum,
                                               int* __restrict__ boff) {
    __shared__ int s[256];
    int t = threadIdx.x;
    s[t] = (t < NB) ? bsum[t] : 0;
    __syncthreads();
    for (int off = 1; off < 256; off <<= 1) {
        int v = s[t];
        int a = (t >= off) ? s[t - off] : 0;
        __syncthreads();
        s[t] = v + a;
        __syncthreads();
    }
    if (t < NB) boff[t] = (t == 0) ? 0 : s[t - 1];
}

__global__ __launch_bounds__(256) void k_writeptr(const int* __restrict__ deg,
                                                  const int* __restrict__ boff,
                                                  int* __restrict__ row_ptr,
                                                  float* __restrict__ rinv) {
    __shared__ int s[256];
    int b = blockIdx.x, t = threadIdx.x;
    int i = b * 256 + t;
    int d = (i < NN) ? deg[i] : 0;
    s[t] = d;
    __syncthreads();
    for (int off = 1; off < 256; off <<= 1) {
        int v = s[t];
        int a = (t >= off) ? s[t - off] : 0;
        __syncthreads();
        s[t] = v + a;
        __syncthreads();
    }
    if (i < NN) {
        int pos = boff[b] + s[t] - d;
        row_ptr[i] = pos;
        rinv[i] = 1.0f / (float)max(d, 1);
    }
    if (b == 0 && t == 0) row_ptr[NN] = NE;
}

// deterministic fill: p = row_ptr[dst] + rank[e]; no atomics.
__global__ void k_fill(const int* __restrict__ ei,
                       const int* __restrict__ row_ptr,
                       const ushort* __restrict__ rank, ushort* __restrict__ col) {
    int e = blockIdx.x * 256 + threadIdx.x;
    if (e >= NE) return;
    int is64 = ei_is64(ei);
    int sv = is64 ? ei[2 * e] : ei[e];
    int dv = is64 ? ei[2 * NE + 2 * e] : ei[NE + e];
    int p = row_ptr[dv] + (int)rank[e];
    col[p] = (ushort)sv;
}

// ---------------- mean aggregation (measured-best structure) ------------------
// One wave per node; lane = bf16 pair. One col load covers 64 edges; row
// gathers are independent 256B coalesced wave loads (masked ragged tail).
// ~58us/layer floor: chip-level random-64B-line service bound (sc0, occupancy,
// MLP, fusion variants all within ~10%).
__global__ __launch_bounds__(256) void k_agg3(const ushort* __restrict__ h,
                                              const int* __restrict__ row_ptr,
                                              const ushort* __restrict__ col,
                                              const float* __restrict__ rinv,
                                              ushort* __restrict__ mean) {
    int node = blockIdx.x * 4 + (threadIdx.x >> 6);
    if (node >= NN) return;
    int lane = threadIdx.x & 63;
    int beg = row_ptr[node], end = row_ptr[node + 1];
    const uint* hp = (const uint*)h;  // row = 64 uints (128 bf16)
    float a0 = 0.f, a1 = 0.f;
    for (int b = beg; b < end; b += 64) {   // one iteration for deg <= 64
        int n = min(64, end - b);
        int c = (int)col[b + min(lane, n - 1)];
        for (int j0 = 0; j0 < n; j0 += 8) {
#pragma unroll
            for (int j = 0; j < 8; j++) {
                int jj = j0 + j;                     // wave-uniform
                int s = __shfl(c, min(jj, n - 1));   // uniform broadcast
                uint v = hp[s * 64 + lane];          // coalesced 256B row
                float m = (jj < n) ? 1.f : 0.f;
                a0 = fmaf(m, bf_lo(v), a0);
                a1 = fmaf(m, bf_hi(v), a1);
            }
        }
    }
    float r = rinv[node];
    ((uint*)mean)[node * 64 + lane] = rne_bf16(a0 * r) | (rne_bf16(a1 * r) << 16);
}

// ---------------- MFMA GEMM: out = mean@Wl^T + h@Wr^T + b (+ReLU) -------------
__global__ __launch_bounds__(256) void k_gemm_mfma(
    const ushort* __restrict__ Am, const ushort* __restrict__ Ah,
    const ushort* __restrict__ Wlb, const ushort* __restrict__ Wrb,
    const float* __restrict__ bias, float* __restrict__ outf,
    ushort* __restrict__ outb, int relu) {
    const int lane = threadIdx.x & 63;
    const int wave = threadIdx.x >> 6;
    const int l15 = lane & 15;
    const int quad = lane >> 4;
    const int m0 = blockIdx.x * 64 + wave * 16;

    f32x4 acc[8];
#pragma unroll
    for (int t = 0; t < 8; t++) acc[t] = (f32x4){0.f, 0.f, 0.f, 0.f};

    int arow = min(m0 + l15, NN - 1);  // clamp loads; stores guarded below
    const ushort* Arm = Am + (size_t)arow * 128 + quad * 8;
    const ushort* Arh = Ah + (size_t)arow * 128 + quad * 8;
    const int wro = quad * 8;

#pragma unroll
    for (int half = 0; half < 2; half++) {
        const ushort* Ar = half ? Arh : Arm;
        const ushort* W = half ? Wrb : Wlb;
#pragma unroll
        for (int k0 = 0; k0 < 128; k0 += 32) {
            short8 a = *(const short8*)(Ar + k0);
#pragma unroll
            for (int t = 0; t < 8; t++) {
                short8 b = *(const short8*)(W + (size_t)(t * 16 + l15) * 128 + k0 + wro);
                acc[t] = __builtin_amdgcn_mfma_f32_16x16x32_bf16(a, b, acc[t], 0, 0, 0);
            }
        }
    }

    float bb[8];
#pragma unroll
    for (int t = 0; t < 8; t++) bb[t] = bias[t * 16 + l15];

#pragma unroll
    for (int r = 0; r < 4; r++) {
        int row = m0 + quad * 4 + r;  // C/D: row = quad*4 + reg
        if (row < NN) {
#pragma unroll
            for (int t = 0; t < 8; t++) {
                float v = acc[t][r] + bb[t];
                if (relu) v = fmaxf(v, 0.f);
                if (outb) outb[(size_t)row * 128 + t * 16 + l15] = (ushort)rne_bf16(v);
                else outf[(size_t)row * 128 + t * 16 + l15] = v;
            }
        }
    }
}

extern "C" void kernel_launch(void* const* d_in, const int* in_sizes, int n_in,
                              void* d_out, int out_size, void* d_ws, size_t ws_size,
                              hipStream_t stream) {
    const float* x = (const float*)d_in[0];
    const int* ei = (const int*)d_in[1];
    const float* Wl[4] = {(const float*)d_in[2], (const float*)d_in[5],
                          (const float*)d_in[8], (const float*)d_in[11]};
    const float* bl[4] = {(const float*)d_in[3], (const float*)d_in[6],
                          (const float*)d_in[9], (const float*)d_in[12]};
    const float* Wr[4] = {(const float*)d_in[4], (const float*)d_in[7],
                          (const float*)d_in[10], (const float*)d_in[13]};
    float* out = (float*)d_out;

    char* p = (char*)d_ws;
    auto take = [&](size_t bytes) -> char* {
        char* r = p;
        p += (bytes + 255) & ~(size_t)255;
        return r;
    };
    int* deg = (int*)take(NN * 4);
    int* row_ptr = (int*)take((NN + 1) * 4);
    float* rinv = (float*)take(NN * 4);
    int* bsum = (int*)take(NB * 4);
    int* boff = (int*)take(NB * 4);
    ushort* rank = (ushort*)take((size_t)NE * 2);
    ushort* col = (ushort*)take((size_t)NE * 2 + 256);  // +pad
    ushort* xbf = (ushort*)take((size_t)NN * 128 * 2);
    ushort* h1 = (ushort*)take((size_t)NN * 128 * 2);
    ushort* h2 = (ushort*)take((size_t)NN * 128 * 2);
    ushort* meanbf = (ushort*)take((size_t)NN * 128 * 2);
    ushort* wbf = (ushort*)take(8 * 16384 * 2);

    Ptrs8 ps;
    ps.p[0] = Wl[0]; ps.p[1] = Wr[0]; ps.p[2] = Wl[1]; ps.p[3] = Wr[1];
    ps.p[4] = Wl[2]; ps.p[5] = Wr[2]; ps.p[6] = Wl[3]; ps.p[7] = Wr[3];

    // prep: casts + degree count in ONE dispatch; then scan + fill (CSR reused
    // by all 4 layers).
    hipMemsetAsync(deg, 0, NN * 4, stream);
    k_prep<<<CAST_B + CVTW_B + CNT_B, 256, 0, stream>>>(x, xbf, ps, wbf, ei, deg,
                                                        rank);
    k_blocksum<<<NB, 256, 0, stream>>>(deg, bsum);
    k_scanb<<<1, 256, 0, stream>>>(bsum, boff);
    k_writeptr<<<NB, 256, 0, stream>>>(deg, boff, row_ptr, rinv);
    k_fill<<<CNT_B, 256, 0, stream>>>(ei, row_ptr, rank, col);

    const ushort* h = xbf;
    ushort* houts[4] = {h1, h2, h1, nullptr};  // final layer -> fp32 d_out
    for (int l = 0; l < 4; l++) {
        k_agg3<<<(NN + 3) / 4, 256, 0, stream>>>(h, row_ptr, col, rinv, meanbf);
        k_gemm_mfma<<<(NN + 63) / 64, 256, 0, stream>>>(
            meanbf, h, wbf + (size_t)(2 * l) * 16384,
            wbf + (size_t)(2 * l + 1) * 16384, bl[l], out, houts[l],
            l == 0 ? 1 : 0);
        h = houts[l];
    }
}